// Round 1
// baseline (309.704 us; speedup 1.0000x reference)
//
#include <hip/hip_runtime.h>
#include <stdint.h>

// FullyConnectedSteerableGeometricProductLayer (G(3,0), 8 blades)
// B=2048, N_IN=N_OUT=512, N_PATHS=20. ALL I/O IS FLOAT32; internal bf16 MFMA.
//
// R7: min-2-phase pipeline (guide T3-minimum + T4 counted vmcnt + T2 swizzle):
//  - raw s_barrier + explicit s_waitcnt (no __syncthreads drain): prefetch
//    loads stay in flight across barriers.
//  - LDS tiles unpadded [128][32] ushort with XOR chunk swizzle
//    slot = c ^ ((row>>1)&3)  -> conflict-free ds_read_b128 / ds_write_b128.
//  - B operand staged via global_load_lds (16B), source column pre-swizzled
//    (linear LDS dest, rule #21). gemm2's W stream is 2-deep (sB[3]),
//    fence waits vmcnt(1) so one W-load rides across each barrier.
//  - gemm2 A operand (pairpack) reg-staged, ds_write to swizzled slot.

#define B_DIM 2048
#define N_DIM 512
#define PLANE (B_DIM * N_DIM)   // 1048576
#define WPLANE (N_DIM * N_DIM)  // 262144
#define KTOT (9 * N_DIM)        // 4608
#define TILE_US (128 * 32)      // ushorts per LDS tile buffer (8 KB)

using frag8 = __attribute__((ext_vector_type(8))) short;  // 8 bf16
using f32x4 = __attribute__((ext_vector_type(4))) float;  // MFMA acc

__device__ __forceinline__ float bf2f(unsigned short u) {
  union { unsigned int i; float f; } v;
  v.i = ((unsigned int)u) << 16;
  return v.f;
}
__device__ __forceinline__ unsigned short f2bf(float f) {  // RNE
  unsigned int u = __float_as_uint(f);
  return (unsigned short)((u + 0x7FFFu + ((u >> 16) & 1u)) >> 16);
}
// two bf16 pairs (dwords a,r) -> packed bf16 products (round-half-up)
__device__ __forceinline__ unsigned int pairpack(unsigned int a, unsigned int r) {
  const float pe = __uint_as_float(a << 16) * __uint_as_float(r << 16);
  const float po = __uint_as_float(a & 0xFFFF0000u) * __uint_as_float(r & 0xFFFF0000u);
  return __builtin_amdgcn_perm(__float_as_uint(po) + 0x8000u,
                               __float_as_uint(pe) + 0x8000u, 0x07060302u);
}

typedef const unsigned int __attribute__((address_space(1)))* gas_t;
typedef unsigned int __attribute__((address_space(3)))* las_t;
// async 16B/lane global->LDS; LDS dest = wave-uniform base + lane*16
__device__ __forceinline__ void gload16(const void* g, void* l) {
  __builtin_amdgcn_global_load_lds((gas_t)g, (las_t)l, 16, 0, 0);
}

// counted fence + raw barrier. N = how many newest vmem ops may stay in flight.
#define PIPE_FENCE(N)                                                  \
  do {                                                                 \
    asm volatile("s_waitcnt vmcnt(" #N ") lgkmcnt(0)" ::: "memory");   \
    __builtin_amdgcn_s_barrier();                                      \
    __builtin_amdgcn_sched_barrier(0);                                 \
  } while (0)

// ---- Cayley tables (verified end-to-end R3/R4/R5): sgn(j,k), p(j,k), grade.
// i(j,k) = P(P(j)^P(k)) with P = swap(3,4) involution (R4/R5-verified).
#define SGN_INIT {                                                     \
  {0,0,0,0,0x8000,0x8000,0x8000,0x8000},                               \
  {0,0,0,0,0x8000,0x8000,0x8000,0x8000},                               \
  {0,0x8000,0,0,0,0,0x8000,0},                                         \
  {0,0x8000,0x8000,0,0x8000,0,0,0x8000},                               \
  {0,0x8000,0,0,0,0,0x8000,0},                                         \
  {0,0x8000,0x8000,0,0x8000,0,0,0x8000},                               \
  {0,0,0x8000,0,0,0x8000,0,0},                                         \
  {0,0,0x8000,0,0,0x8000,0,0} }
#define PJK_INIT {                                                     \
  {0,4,4,4,10,10,10,16},  {5,1,11,11,6,6,17,12},                       \
  {5,11,1,11,6,17,6,12},  {5,11,11,1,17,6,6,12},                       \
  {13,7,7,18,2,14,14,8},  {13,7,18,7,14,2,14,8},                       \
  {13,18,7,7,14,14,2,8},  {19,15,15,15,9,9,9,3} }
#define GR_INIT {0,1,1,1,2,2,2,3}

// ---------------- repack / prebuild (f32 in -> bf16 planes) ----------------

__global__ __launch_bounds__(256) void repack_x(const float* __restrict__ x,
                                                unsigned short* __restrict__ xt) {
  const int t = blockIdx.x * 256 + threadIdx.x;
  const float4 v0 = *(const float4*)(x + (size_t)t * 8);
  const float4 v1 = *(const float4*)(x + (size_t)t * 8 + 4);
  const float v[8] = {v0.x, v0.y, v0.z, v0.w, v1.x, v1.y, v1.z, v1.w};
#pragma unroll
  for (int i = 0; i < 8; ++i) xt[(size_t)i * PLANE + t] = f2bf(v[i]);
}

__global__ __launch_bounds__(256) void repack_wr(const float* __restrict__ wr,
                                                 unsigned short* __restrict__ wrt) {
  const int t = blockIdx.x * 256 + threadIdx.x;
  const float4 v = *(const float4*)(wr + (size_t)t * 4);
  const float p[4] = {v.x, v.y, v.z, v.w};
#pragma unroll
  for (int g = 0; g < 4; ++g) wrt[(size_t)g * WPLANE + t] = f2bf(p[g]);
}

__global__ __launch_bounds__(256) void build_W(const float* __restrict__ w,
                                               const float* __restrict__ wl,
                                               unsigned short* __restrict__ Wall) {
  constexpr int PJK[8][8] = PJK_INIT;
  constexpr unsigned short SGN[8][8] = SGN_INIT;
  constexpr int GR[8] = GR_INIT;
  const int t = blockIdx.x * 256 + threadIdx.x;
  const int m = t >> 9, n = t & 511;
  const float* wrow = w + (size_t)t * 20;
  const float* wlrow = wl + (size_t)t * 4;
  unsigned short w20[20];
#pragma unroll
  for (int p = 0; p < 20; ++p) w20[p] = f2bf(wrow[p]);
  unsigned short wl4[4];
#pragma unroll
  for (int g = 0; g < 4; ++g) wl4[g] = f2bf(wlrow[g]);
#pragma unroll
  for (int j = 0; j < 8; ++j) {
    const size_t base = ((size_t)j * N_DIM + m) * KTOT + n;
#pragma unroll
    for (int k = 0; k < 8; ++k)
      Wall[base + (size_t)k * N_DIM] = (unsigned short)(w20[PJK[j][k]] ^ SGN[j][k]);
    Wall[base + (size_t)8 * N_DIM] = wl4[GR[j]];
  }
}

__global__ __launch_bounds__(256) void normk(unsigned short* __restrict__ xre,
                                             const float* __restrict__ na) {
  const int t = blockIdx.x * 256 + threadIdx.x;
  const int n = t & 511;
  float v[8];
#pragma unroll
  for (int p = 0; p < 8; ++p) v[p] = bf2f(xre[(size_t)p * PLANE + t]);
  const float n0 = fabsf(v[0]);
  const float n1 = sqrtf(v[1] * v[1] + v[2] * v[2] + v[3] * v[3]);
  const float n2 = sqrtf(v[4] * v[4] + v[5] * v[5] + v[6] * v[6]);
  const float n3 = fabsf(v[7]);
  float f[4];
  const float nm[4] = {n0, n1, n2, n3};
#pragma unroll
  for (int g = 0; g < 4; ++g) {
    const float a = na[n * 4 + g];
    const float sig = 1.0f / (1.0f + __expf(-a));
    f[g] = sig * (nm[g] - 1.0f) + 1.0f + 1e-6f;
  }
  v[0] /= f[0];
  v[1] /= f[1]; v[2] /= f[1]; v[3] /= f[1];
  v[4] /= f[2]; v[5] /= f[2]; v[6] /= f[2];
  v[7] /= f[3];
#pragma unroll
  for (int p = 0; p < 8; ++p) xre[(size_t)p * PLANE + t] = f2bf(v[p]);
  xre[(size_t)8 * PLANE + t] = 0x3F80;  // 1.0 plane -> 'left' term in gemm2
}

// ------- gemm1: xre[z] = xt[z] * wrt[g(z)]^T  (128x128, 8 waves) -----------
// min-2-phase: gload both operands (swizzled source cols), raw barrier,
// vmcnt(0) at fence (loads overlap the ds_read+MFMA of the current chunk).

__global__ __launch_bounds__(512, 4) void gemm1(const unsigned short* __restrict__ xt,
                                                const unsigned short* __restrict__ wrt,
                                                unsigned short* __restrict__ xre) {
  constexpr int GR[8] = GR_INIT;
  __shared__ unsigned short sA[2][TILE_US];
  __shared__ unsigned short sB[2][TILE_US];
  const int bm0 = blockIdx.x * 128, bn0 = blockIdx.y * 128, z = blockIdx.z;
  const unsigned short* A = xt + (size_t)z * PLANE;
  const unsigned short* Bm = wrt + (size_t)GR[z] * WPLANE;
  unsigned short* C = xre + (size_t)z * PLANE;

  const int tid = (int)threadIdx.x;
  const int lane = tid & 63, wave = tid >> 6;
  const int wm = (wave >> 2) * 64, wn = (wave & 3) * 32;
  const int fr = lane & 15, quad = lane >> 4;
  const int row = tid >> 2;
  // swizzled 16B-chunk offset (ushorts): chunk (tid&3) XOR row-hash
  const int ks = (((tid & 3) ^ ((tid >> 3) & 3))) * 8;
  const int wbase = wave * 512;  // per-wave linear LDS dest (ushorts)

  const unsigned short* pa = A + (size_t)(bm0 + row) * N_DIM + ks;
  const unsigned short* pb = Bm + (size_t)(bn0 + row) * N_DIM + ks;

  // frag read offsets (apply the same XOR on read)
  const int msw = (fr >> 1) & 3;
  const int rdA = (wm + fr) * 32 + (quad ^ msw) * 8;
  const int rdB = (wn + fr) * 32 + (quad ^ msw) * 8;

  f32x4 acc[4][2];
#pragma unroll
  for (int mt = 0; mt < 4; ++mt)
#pragma unroll
    for (int nt = 0; nt < 2; ++nt) acc[mt][nt] = (f32x4){0.f, 0.f, 0.f, 0.f};

  // prologue: stage chunk 0
  gload16(pa, &sA[0][wbase]);
  gload16(pb, &sB[0][wbase]);
  PIPE_FENCE(0);

  for (int it = 0; it < 16; ++it) {
    const int c = it & 1;
    if (it < 15) {
      gload16(pa + ((it + 1) << 5), &sA[c ^ 1][wbase]);
      gload16(pb + ((it + 1) << 5), &sB[c ^ 1][wbase]);
    }
    frag8 af[4], bfr[2];
#pragma unroll
    for (int t = 0; t < 4; ++t) af[t] = *(const frag8*)&sA[c][rdA + t * 512];
#pragma unroll
    for (int t = 0; t < 2; ++t) bfr[t] = *(const frag8*)&sB[c][rdB + t * 512];
#pragma unroll
    for (int mt = 0; mt < 4; ++mt)
#pragma unroll
      for (int nt = 0; nt < 2; ++nt)
        acc[mt][nt] = __builtin_amdgcn_mfma_f32_16x16x32_bf16(af[mt], bfr[nt], acc[mt][nt], 0, 0, 0);
    if (it < 15) PIPE_FENCE(0);
  }
  // C/D: col = lane&15, row = quad*4 + reg
#pragma unroll
  for (int mt = 0; mt < 4; ++mt) {
    const int row0 = bm0 + wm + mt * 16 + quad * 4;
#pragma unroll
    for (int nt = 0; nt < 2; ++nt) {
      const int col = bn0 + wn + nt * 16 + fr;
#pragma unroll
      for (int r = 0; r < 4; ++r)
        C[(size_t)(row0 + r) * N_DIM + col] = f2bf(acc[mt][nt][r]);
    }
  }
}

// ------- gemm2: out = (pair * Wall_j + bias)/sqrt(2), K=4608 ---------------
// A (pairpack) reg-staged 1 chunk ahead -> swizzled ds_write (sA dbuf).
// B (Wall) via global_load_lds, 2 chunks ahead (sB triple buffer): the
// fence waits vmcnt(1) so one W-load stays in flight across each barrier.

__global__ __launch_bounds__(512, 4) void gemm2(const unsigned short* __restrict__ xt,
                                                const unsigned short* __restrict__ xre,
                                                const unsigned short* __restrict__ Wall,
                                                const float* __restrict__ bl,
                                                float* __restrict__ out) {
  __shared__ unsigned short sA[2][TILE_US];
  __shared__ unsigned short sB3[3][TILE_US];
  const int bm0 = blockIdx.x * 128, bn0 = blockIdx.y * 128, j = blockIdx.z;

  const int tid = (int)threadIdx.x;
  const int lane = tid & 63, wave = tid >> 6;
  const int wm = (wave >> 2) * 64, wn = (wave & 3) * 32;
  const int fr = lane & 15, quad = lane >> 4;
  const int row = tid >> 2, k8 = (tid & 3) * 8;
  const int ks = (((tid & 3) ^ ((tid >> 3) & 3))) * 8;
  const int wbase = wave * 512;
  const int pj = (j == 3 || j == 4) ? (j ^ 7) : j;  // P(j)

  f32x4 acc[4][2];
#pragma unroll
  for (int mt = 0; mt < 4; ++mt)
#pragma unroll
    for (int nt = 0; nt < 2; ++nt) acc[mt][nt] = (f32x4){0.f, 0.f, 0.f, 0.f};

  // A-sources: un-swizzled global col (data goes through regs anyway)
  const size_t arow = (size_t)(bm0 + row) * N_DIM + k8;
  // B-source: swizzled global col (linear LDS dest via global_load_lds)
  const unsigned short* pwb = Wall + ((size_t)j * N_DIM + bn0 + row) * KTOT + ks;

  // plane index of xt for slice sl: ie = P(pj ^ P(sl)); sl=8 -> j
  auto ieof = [&](int sl) -> int {
    int ps = (sl == 3 || sl == 4) ? (sl ^ 7) : sl;
    int ix = pj ^ ps;
    ix = (ix == 3 || ix == 4) ? (ix ^ 7) : ix;
    return (sl == 8) ? j : ix;
  };

  const int msw = (fr >> 1) & 3;
  const int rdA = (wm + fr) * 32 + (quad ^ msw) * 8;
  const int rdB = (wn + fr) * 32 + (quad ^ msw) * 8;
  const int wrA = row * 32 + ks;  // swizzled sA write slot

  // ---- prologue: chunk 0 staged, chunk-1 W-load left in flight
  {
    uint4 rx = *(const uint4*)(xt + ((size_t)ieof(0) << 20) + arow);
    uint4 rr = *(const uint4*)(xre + arow);
    gload16(pwb, &sB3[0][wbase]);
    gload16(pwb + 32, &sB3[1][wbase]);
    uint4 o;
    o.x = pairpack(rx.x, rr.x);
    o.y = pairpack(rx.y, rr.y);
    o.z = pairpack(rx.z, rr.z);
    o.w = pairpack(rx.w, rr.w);
    *(uint4*)&sA[0][wrA] = o;
  }
  PIPE_FENCE(1);

  uint4 rx, rr;
  int cb = 0, wb = 2;  // sB3 read / write rotating indices
  for (int it = 0; it < 144; ++it) {
    const int c2 = it & 1;
    if (it < 143) {
      const int kn = it + 1;
      const int slk = kn >> 4, n0k = (kn & 15) << 5;
      int ps = (slk == 3 || slk == 4) ? (slk ^ 7) : slk;
      int ix = pj ^ ps;
      ix = (ix == 3 || ix == 4) ? (ix ^ 7) : ix;
      const int ie = (slk == 8) ? j : ix;
      rx = *(const uint4*)(xt + ((size_t)ie << 20) + arow + n0k);
      rr = *(const uint4*)(xre + ((size_t)slk << 20) + arow + n0k);
      if (it < 142) gload16(pwb + (size_t)(it + 2) * 32, &sB3[wb][wbase]);
    }
    frag8 af[4], bfr[2];
#pragma unroll
    for (int t = 0; t < 4; ++t) af[t] = *(const frag8*)&sA[c2][rdA + t * 512];
#pragma unroll
    for (int t = 0; t < 2; ++t) bfr[t] = *(const frag8*)&sB3[cb][rdB + t * 512];
#pragma unroll
    for (int mt = 0; mt < 4; ++mt)
#pragma unroll
      for (int nt = 0; nt < 2; ++nt)
        acc[mt][nt] = __builtin_amdgcn_mfma_f32_16x16x32_bf16(af[mt], bfr[nt], acc[mt][nt], 0, 0, 0);
    if (it < 143) {
      uint4 o;
      o.x = pairpack(rx.x, rr.x);
      o.y = pairpack(rx.y, rr.y);
      o.z = pairpack(rx.z, rr.z);
      o.w = pairpack(rx.w, rr.w);
      *(uint4*)&sA[c2 ^ 1][wrA] = o;
      PIPE_FENCE(1);
    }
    cb = (cb + 1 == 3) ? 0 : cb + 1;
    wb = (wb + 1 == 3) ? 0 : wb + 1;
  }

  const float inv = 0.70710678118654752f;
#pragma unroll
  for (int nt = 0; nt < 2; ++nt) {
    const int col = bn0 + wn + nt * 16 + fr;  // m (output neuron)
    const float bias = (j == 0) ? bl[col] : 0.0f;
#pragma unroll
    for (int mt = 0; mt < 4; ++mt) {
      const int row0 = bm0 + wm + mt * 16 + quad * 4;  // b
#pragma unroll
      for (int r = 0; r < 4; ++r)
        out[((size_t)(row0 + r) * N_DIM + col) * 8 + j] =
            (acc[mt][nt][r] + bias) * inv;
    }
  }
}

// ---------------- launch ----------------

extern "C" void kernel_launch(void* const* d_in, const int* in_sizes, int n_in,
                              void* d_out, int out_size, void* d_ws, size_t ws_size,
                              hipStream_t stream) {
  const float* x = (const float*)d_in[0];   // (2048,512,8)  f32
  const float* w = (const float*)d_in[1];   // (512,512,20)  f32
  const float* wr = (const float*)d_in[2];  // (512,512,4)   f32
  const float* wl = (const float*)d_in[3];  // (512,512,4)   f32
  const float* bl = (const float*)d_in[4];  // (512,)        f32
  const float* na = (const float*)d_in[5];  // (1,512,4)     f32
  float* out = (float*)d_out;               // (2048,512,8)  f32

  char* ws = (char*)d_ws;
  unsigned short* xt = (unsigned short*)(ws);                  // 16 MB
  unsigned short* xre = (unsigned short*)(ws + 16777216);      // 18 MB
  unsigned short* wrt = (unsigned short*)(ws + 35651584);      //  2 MB
  unsigned short* Wall = (unsigned short*)(ws + 37748736);     // 36 MB
  // total ws use: 75,497,472 B

  repack_x<<<4096, 256, 0, stream>>>(x, xt);
  repack_wr<<<1024, 256, 0, stream>>>(wr, wrt);
  build_W<<<1024, 256, 0, stream>>>(w, wl, Wall);
  gemm1<<<dim3(16, 4, 8), 512, 0, stream>>>(xt, wrt, xre);
  normk<<<4096, 256, 0, stream>>>(xre, na);
  gemm2<<<dim3(16, 4, 8), 512, 0, stream>>>(xt, xre, Wall, bl, out);
}

// Round 2
// 305.603 us; speedup vs baseline: 1.0134x; 1.0134x over previous
//
#include <hip/hip_runtime.h>
#include <stdint.h>

// FullyConnectedSteerableGeometricProductLayer (G(3,0), 8 blades)
// B=2048, N_IN=N_OUT=512, N_PATHS=20. ALL I/O IS FLOAT32; internal bf16 MFMA.
//
// R8: fixed pipeline discipline (R7 post-mortem):
//  - fence = asm{s_waitcnt vmcnt(N) lgkmcnt(0); s_barrier} with "memory"
//    clobber only -- no sched_barrier(0) pinning (m141 lesson).
//  - vmcnt counts sized in OPS: prefetch ops ride the barrier; in-order
//    vmcnt retirement of the A-register loads forces the needed W tile
//    landed before each barrier (2-iteration latency cover, ~1200 cy).
//  - gemm2: A regs double-buffered (tile it+2 in flight), W 3-ahead in a
//    quad-buffered LDS ring. gemm1: both operands 3-ahead, quad-buffered.
//  - LDS XOR chunk swizzle kept (R7: bank conflicts == 0).

#define B_DIM 2048
#define N_DIM 512
#define PLANE (B_DIM * N_DIM)   // 1048576
#define WPLANE (N_DIM * N_DIM)  // 262144
#define KTOT (9 * N_DIM)        // 4608
#define TILE_US (128 * 32)      // ushorts per LDS tile buffer (8 KB)

using frag8 = __attribute__((ext_vector_type(8))) short;  // 8 bf16
using f32x4 = __attribute__((ext_vector_type(4))) float;  // MFMA acc

__device__ __forceinline__ float bf2f(unsigned short u) {
  union { unsigned int i; float f; } v;
  v.i = ((unsigned int)u) << 16;
  return v.f;
}
__device__ __forceinline__ unsigned short f2bf(float f) {  // RNE
  unsigned int u = __float_as_uint(f);
  return (unsigned short)((u + 0x7FFFu + ((u >> 16) & 1u)) >> 16);
}
// two bf16 pairs (dwords a,r) -> packed bf16 products (round-half-up)
__device__ __forceinline__ unsigned int pairpack(unsigned int a, unsigned int r) {
  const float pe = __uint_as_float(a << 16) * __uint_as_float(r << 16);
  const float po = __uint_as_float(a & 0xFFFF0000u) * __uint_as_float(r & 0xFFFF0000u);
  return __builtin_amdgcn_perm(__float_as_uint(po) + 0x8000u,
                               __float_as_uint(pe) + 0x8000u, 0x07060302u);
}

typedef const unsigned int __attribute__((address_space(1)))* gas_t;
typedef unsigned int __attribute__((address_space(3)))* las_t;
// async 16B/lane global->LDS; LDS dest = wave-uniform base + lane*16
__device__ __forceinline__ void gload16(const void* g, void* l) {
  __builtin_amdgcn_global_load_lds((gas_t)g, (las_t)l, 16, 0, 0);
}

// counted fence + raw barrier, opaque to the memory scheduler but NOT a
// global scheduling pin. N = newest vmem ops allowed to stay in flight.
#define PIPE_FENCE(N)                                                       \
  asm volatile("s_waitcnt vmcnt(" #N ") lgkmcnt(0)\n\ts_barrier" ::: "memory")

// ---- Cayley tables (verified end-to-end R3/R4/R5): sgn(j,k), p(j,k), grade.
// i(j,k) = P(P(j)^P(k)) with P = swap(3,4) involution (R4/R5-verified).
#define SGN_INIT {                                                     \
  {0,0,0,0,0x8000,0x8000,0x8000,0x8000},                               \
  {0,0,0,0,0x8000,0x8000,0x8000,0x8000},                               \
  {0,0x8000,0,0,0,0,0x8000,0},                                         \
  {0,0x8000,0x8000,0,0x8000,0,0,0x8000},                               \
  {0,0x8000,0,0,0,0,0x8000,0},                                         \
  {0,0x8000,0x8000,0,0x8000,0,0,0x8000},                               \
  {0,0,0x8000,0,0,0x8000,0,0},                                         \
  {0,0,0x8000,0,0,0x8000,0,0} }
#define PJK_INIT {                                                     \
  {0,4,4,4,10,10,10,16},  {5,1,11,11,6,6,17,12},                       \
  {5,11,1,11,6,17,6,12},  {5,11,11,1,17,6,6,12},                       \
  {13,7,7,18,2,14,14,8},  {13,7,18,7,14,2,14,8},                       \
  {13,18,7,7,14,14,2,8},  {19,15,15,15,9,9,9,3} }
#define GR_INIT {0,1,1,1,2,2,2,3}

// ---------------- repack / prebuild (f32 in -> bf16 planes) ----------------

__global__ __launch_bounds__(256) void repack_x(const float* __restrict__ x,
                                                unsigned short* __restrict__ xt) {
  const int t = blockIdx.x * 256 + threadIdx.x;
  const float4 v0 = *(const float4*)(x + (size_t)t * 8);
  const float4 v1 = *(const float4*)(x + (size_t)t * 8 + 4);
  const float v[8] = {v0.x, v0.y, v0.z, v0.w, v1.x, v1.y, v1.z, v1.w};
#pragma unroll
  for (int i = 0; i < 8; ++i) xt[(size_t)i * PLANE + t] = f2bf(v[i]);
}

__global__ __launch_bounds__(256) void repack_wr(const float* __restrict__ wr,
                                                 unsigned short* __restrict__ wrt) {
  const int t = blockIdx.x * 256 + threadIdx.x;
  const float4 v = *(const float4*)(wr + (size_t)t * 4);
  const float p[4] = {v.x, v.y, v.z, v.w};
#pragma unroll
  for (int g = 0; g < 4; ++g) wrt[(size_t)g * WPLANE + t] = f2bf(p[g]);
}

__global__ __launch_bounds__(256) void build_W(const float* __restrict__ w,
                                               const float* __restrict__ wl,
                                               unsigned short* __restrict__ Wall) {
  constexpr int PJK[8][8] = PJK_INIT;
  constexpr unsigned short SGN[8][8] = SGN_INIT;
  constexpr int GR[8] = GR_INIT;
  const int t = blockIdx.x * 256 + threadIdx.x;
  const int m = t >> 9, n = t & 511;
  const float* wrow = w + (size_t)t * 20;
  const float* wlrow = wl + (size_t)t * 4;
  unsigned short w20[20];
#pragma unroll
  for (int p = 0; p < 20; ++p) w20[p] = f2bf(wrow[p]);
  unsigned short wl4[4];
#pragma unroll
  for (int g = 0; g < 4; ++g) wl4[g] = f2bf(wlrow[g]);
#pragma unroll
  for (int j = 0; j < 8; ++j) {
    const size_t base = ((size_t)j * N_DIM + m) * KTOT + n;
#pragma unroll
    for (int k = 0; k < 8; ++k)
      Wall[base + (size_t)k * N_DIM] = (unsigned short)(w20[PJK[j][k]] ^ SGN[j][k]);
    Wall[base + (size_t)8 * N_DIM] = wl4[GR[j]];
  }
}

__global__ __launch_bounds__(256) void normk(unsigned short* __restrict__ xre,
                                             const float* __restrict__ na) {
  const int t = blockIdx.x * 256 + threadIdx.x;
  const int n = t & 511;
  float v[8];
#pragma unroll
  for (int p = 0; p < 8; ++p) v[p] = bf2f(xre[(size_t)p * PLANE + t]);
  const float n0 = fabsf(v[0]);
  const float n1 = sqrtf(v[1] * v[1] + v[2] * v[2] + v[3] * v[3]);
  const float n2 = sqrtf(v[4] * v[4] + v[5] * v[5] + v[6] * v[6]);
  const float n3 = fabsf(v[7]);
  float f[4];
  const float nm[4] = {n0, n1, n2, n3};
#pragma unroll
  for (int g = 0; g < 4; ++g) {
    const float a = na[n * 4 + g];
    const float sig = 1.0f / (1.0f + __expf(-a));
    f[g] = sig * (nm[g] - 1.0f) + 1.0f + 1e-6f;
  }
  v[0] /= f[0];
  v[1] /= f[1]; v[2] /= f[1]; v[3] /= f[1];
  v[4] /= f[2]; v[5] /= f[2]; v[6] /= f[2];
  v[7] /= f[3];
#pragma unroll
  for (int p = 0; p < 8; ++p) xre[(size_t)p * PLANE + t] = f2bf(v[p]);
  xre[(size_t)8 * PLANE + t] = 0x3F80;  // 1.0 plane -> 'left' term in gemm2
}

// ------- gemm1: xre[z] = xt[z] * wrt[g(z)]^T  (128x128, 8 waves) -----------
// Quad-buffered, 3 tiles ahead via global_load_lds. Fence vmcnt(4) lets the
// two newest tiles' loads (4 ops) ride the barrier; in-order retirement
// guarantees tile it+1 landed.

__global__ __launch_bounds__(512, 4) void gemm1(const unsigned short* __restrict__ xt,
                                                const unsigned short* __restrict__ wrt,
                                                unsigned short* __restrict__ xre) {
  constexpr int GR[8] = GR_INIT;
  __shared__ __attribute__((aligned(16))) unsigned short sA4[4][TILE_US];
  __shared__ __attribute__((aligned(16))) unsigned short sB4[4][TILE_US];
  const int bm0 = blockIdx.x * 128, bn0 = blockIdx.y * 128, z = blockIdx.z;
  const unsigned short* A = xt + (size_t)z * PLANE;
  const unsigned short* Bm = wrt + (size_t)GR[z] * WPLANE;
  unsigned short* C = xre + (size_t)z * PLANE;

  const int tid = (int)threadIdx.x;
  const int lane = tid & 63, wave = tid >> 6;
  const int wm = (wave >> 2) * 64, wn = (wave & 3) * 32;
  const int fr = lane & 15, quad = lane >> 4;
  const int row = tid >> 2;
  // swizzled 16B-chunk column (ushorts): chunk (tid&3) XOR row-hash
  const int ks = (((tid & 3) ^ ((tid >> 3) & 3))) * 8;
  const int wbase = wave * 512;  // per-wave linear LDS dest (ushorts)

  const unsigned short* pa = A + (size_t)(bm0 + row) * N_DIM + ks;
  const unsigned short* pb = Bm + (size_t)(bn0 + row) * N_DIM + ks;

  // frag read offsets (same XOR on read)
  const int msw = (fr >> 1) & 3;
  const int rdA = (wm + fr) * 32 + (quad ^ msw) * 8;
  const int rdB = (wn + fr) * 32 + (quad ^ msw) * 8;

  f32x4 acc[4][2];
#pragma unroll
  for (int mt = 0; mt < 4; ++mt)
#pragma unroll
    for (int nt = 0; nt < 2; ++nt) acc[mt][nt] = (f32x4){0.f, 0.f, 0.f, 0.f};

  // prologue: tiles 0..2 staged/in-flight (6 ops); need tile0 -> allow 4
  gload16(pa, &sA4[0][wbase]);       gload16(pb, &sB4[0][wbase]);
  gload16(pa + 32, &sA4[1][wbase]);  gload16(pb + 32, &sB4[1][wbase]);
  gload16(pa + 64, &sA4[2][wbase]);  gload16(pb + 64, &sB4[2][wbase]);
  PIPE_FENCE(4);

#pragma unroll 2
  for (int it = 0; it < 16; ++it) {
    if (it < 13) {
      gload16(pa + ((it + 3) << 5), &sA4[(it + 3) & 3][wbase]);
      gload16(pb + ((it + 3) << 5), &sB4[(it + 3) & 3][wbase]);
    }
    frag8 af[4], bfr[2];
#pragma unroll
    for (int t = 0; t < 4; ++t) af[t] = *(const frag8*)&sA4[it & 3][rdA + t * 512];
#pragma unroll
    for (int t = 0; t < 2; ++t) bfr[t] = *(const frag8*)&sB4[it & 3][rdB + t * 512];
#pragma unroll
    for (int mt = 0; mt < 4; ++mt)
#pragma unroll
      for (int nt = 0; nt < 2; ++nt)
        acc[mt][nt] = __builtin_amdgcn_mfma_f32_16x16x32_bf16(af[mt], bfr[nt], acc[mt][nt], 0, 0, 0);
    // fence: need tile it+1 landed; tiles it+2, it+3 (4 ops) may ride
    if (it < 13) PIPE_FENCE(4);
    else if (it == 13) PIPE_FENCE(2);
    else if (it == 14) PIPE_FENCE(0);
  }
  // C/D: col = lane&15, row = quad*4 + reg
#pragma unroll
  for (int mt = 0; mt < 4; ++mt) {
    const int row0 = bm0 + wm + mt * 16 + quad * 4;
#pragma unroll
    for (int nt = 0; nt < 2; ++nt) {
      const int col = bn0 + wn + nt * 16 + fr;
#pragma unroll
      for (int r = 0; r < 4; ++r)
        C[(size_t)(row0 + r) * N_DIM + col] = f2bf(acc[mt][nt][r]);
    }
  }
}

// ------- gemm2: out = (pair * Wall_j + bias)/sqrt(2), K=4608 ---------------
// A (pairpack) reg double-buffered: tile it+2 loads in flight, tile it+1
// regs packed+written this iter. W via global_load_lds 3 ahead (quad ring).
// Steady fence vmcnt(4) = {rxN,rrN,W(it+3)} ride; pairpack's register wait
// (in-order vmcnt) forces W(it+1) landed before every barrier.

__global__ __launch_bounds__(512, 4) void gemm2(const unsigned short* __restrict__ xt,
                                                const unsigned short* __restrict__ xre,
                                                const unsigned short* __restrict__ Wall,
                                                const float* __restrict__ bl,
                                                float* __restrict__ out) {
  __shared__ __attribute__((aligned(16))) unsigned short sA2[2][TILE_US];
  __shared__ __attribute__((aligned(16))) unsigned short sB4[4][TILE_US];
  const int bm0 = blockIdx.x * 128, bn0 = blockIdx.y * 128, j = blockIdx.z;

  const int tid = (int)threadIdx.x;
  const int lane = tid & 63, wave = tid >> 6;
  const int wm = (wave >> 2) * 64, wn = (wave & 3) * 32;
  const int fr = lane & 15, quad = lane >> 4;
  const int row = tid >> 2, k8 = (tid & 3) * 8;
  const int ks = (((tid & 3) ^ ((tid >> 3) & 3))) * 8;
  const int wbase = wave * 512;
  const int pj = (j == 3 || j == 4) ? (j ^ 7) : j;  // P(j)

  f32x4 acc[4][2];
#pragma unroll
  for (int mt = 0; mt < 4; ++mt)
#pragma unroll
    for (int nt = 0; nt < 2; ++nt) acc[mt][nt] = (f32x4){0.f, 0.f, 0.f, 0.f};

  // A-sources: un-swizzled global col (data goes through regs anyway)
  const size_t arow = (size_t)(bm0 + row) * N_DIM + k8;
  // B-source: swizzled global col (linear LDS dest via global_load_lds)
  const unsigned short* pwb = Wall + ((size_t)j * N_DIM + bn0 + row) * KTOT + ks;

  // plane index of xt for slice sl: ie = P(pj ^ P(sl)); sl=8 -> j
  auto ieof = [&](int sl) -> int {
    int ps = (sl == 3 || sl == 4) ? (sl ^ 7) : sl;
    int ix = pj ^ ps;
    ix = (ix == 3 || ix == 4) ? (ix ^ 7) : ix;
    return (sl == 8) ? j : ix;
  };

  const int msw = (fr >> 1) & 3;
  const int rdA = (wm + fr) * 32 + (quad ^ msw) * 8;
  const int rdB = (wn + fr) * 32 + (quad ^ msw) * 8;
  const int wrA = row * 32 + ks;  // swizzled sA write slot

  uint4 rxP, rrP;  // A regs for tile it+1 (pending pairpack)
  // ---- prologue: tile0 packed+written; tile1 A-regs and W0..W2 in flight
  {
    const uint4 r0x = *(const uint4*)(xt + ((size_t)ieof(0) << 20) + arow);
    const uint4 r0r = *(const uint4*)(xre + arow);
    gload16(pwb, &sB4[0][wbase]);
    gload16(pwb + 32, &sB4[1][wbase]);
    gload16(pwb + 64, &sB4[2][wbase]);
    rxP = *(const uint4*)(xt + ((size_t)ieof(0) << 20) + arow + 32);  // tile1
    rrP = *(const uint4*)(xre + arow + 32);
    uint4 o;
    o.x = pairpack(r0x.x, r0r.x);
    o.y = pairpack(r0x.y, r0r.y);
    o.z = pairpack(r0x.z, r0r.z);
    o.w = pairpack(r0x.w, r0r.w);
    *(uint4*)&sA2[0][wrA] = o;
  }
  // outstanding: W1,W2,rxP,rrP (4 ops); W0 (older) forced landed
  PIPE_FENCE(4);

#pragma unroll 2
  for (int it = 0; it < 144; ++it) {
    const int c2 = it & 1;
    uint4 rxN, rrN;
    if (it < 142) {  // A loads for tile it+2
      const int kn = it + 2;
      const int slk = kn >> 4, n0k = (kn & 15) << 5;
      int ps = (slk == 3 || slk == 4) ? (slk ^ 7) : slk;
      int ix = pj ^ ps;
      ix = (ix == 3 || ix == 4) ? (ix ^ 7) : ix;
      const int ie = (slk == 8) ? j : ix;
      rxN = *(const uint4*)(xt + ((size_t)ie << 20) + arow + n0k);
      rrN = *(const uint4*)(xre + ((size_t)slk << 20) + arow + n0k);
    }
    if (it < 141) gload16(pwb + (size_t)(it + 3) * 32, &sB4[(it + 3) & 3][wbase]);

    frag8 af[4], bfr[2];
#pragma unroll
    for (int t = 0; t < 4; ++t) af[t] = *(const frag8*)&sA2[c2][rdA + t * 512];
#pragma unroll
    for (int t = 0; t < 2; ++t) bfr[t] = *(const frag8*)&sB4[it & 3][rdB + t * 512];
#pragma unroll
    for (int mt = 0; mt < 4; ++mt)
#pragma unroll
      for (int nt = 0; nt < 2; ++nt)
        acc[mt][nt] = __builtin_amdgcn_mfma_f32_16x16x32_bf16(af[mt], bfr[nt], acc[mt][nt], 0, 0, 0);

    if (it < 143) {  // pack tile it+1 (regs loaded last iter), write sA
      uint4 o;
      o.x = pairpack(rxP.x, rrP.x);
      o.y = pairpack(rxP.y, rrP.y);
      o.z = pairpack(rxP.z, rrP.z);
      o.w = pairpack(rxP.w, rrP.w);
      *(uint4*)&sA2[c2 ^ 1][wrA] = o;
    }
    rxP = rxN;
    rrP = rrN;
    // fence: allow {rxN,rrN,W(it+3)} (4 ops) to ride; older all retired
    if (it < 141) PIPE_FENCE(4);
    else if (it == 141) PIPE_FENCE(3);
    else if (it == 142) PIPE_FENCE(0);
  }

  const float inv = 0.70710678118654752f;
#pragma unroll
  for (int nt = 0; nt < 2; ++nt) {
    const int col = bn0 + wn + nt * 16 + fr;  // m (output neuron)
    const float bias = (j == 0) ? bl[col] : 0.0f;
#pragma unroll
    for (int mt = 0; mt < 4; ++mt) {
      const int row0 = bm0 + wm + mt * 16 + quad * 4;  // b
#pragma unroll
      for (int r = 0; r < 4; ++r)
        out[((size_t)(row0 + r) * N_DIM + col) * 8 + j] =
            (acc[mt][nt][r] + bias) * inv;
    }
  }
}

// ---------------- launch ----------------

extern "C" void kernel_launch(void* const* d_in, const int* in_sizes, int n_in,
                              void* d_out, int out_size, void* d_ws, size_t ws_size,
                              hipStream_t stream) {
  const float* x = (const float*)d_in[0];   // (2048,512,8)  f32
  const float* w = (const float*)d_in[1];   // (512,512,20)  f32
  const float* wr = (const float*)d_in[2];  // (512,512,4)   f32
  const float* wl = (const float*)d_in[3];  // (512,512,4)   f32
  const float* bl = (const float*)d_in[4];  // (512,)        f32
  const float* na = (const float*)d_in[5];  // (1,512,4)     f32
  float* out = (float*)d_out;               // (2048,512,8)  f32

  char* ws = (char*)d_ws;
  unsigned short* xt = (unsigned short*)(ws);                  // 16 MB
  unsigned short* xre = (unsigned short*)(ws + 16777216);      // 18 MB
  unsigned short* wrt = (unsigned short*)(ws + 35651584);      //  2 MB
  unsigned short* Wall = (unsigned short*)(ws + 37748736);     // 36 MB
  // total ws use: 75,497,472 B

  repack_x<<<4096, 256, 0, stream>>>(x, xt);
  repack_wr<<<1024, 256, 0, stream>>>(wr, wrt);
  build_W<<<1024, 256, 0, stream>>>(w, wl, Wall);
  gemm1<<<dim3(16, 4, 8), 512, 0, stream>>>(xt, wrt, xre);
  normk<<<4096, 256, 0, stream>>>(xre, na);
  gemm2<<<dim3(16, 4, 8), 512, 0, stream>>>(xt, xre, Wall, bl, out);
}